// Round 2
// baseline (365.964 us; speedup 1.0000x reference)
//
#include <hip/hip_runtime.h>
#include <hip/hip_bf16.h>
#include <stdint.h>

// Problem constants: B=32, D=64, H=64, W=64, K=512; N = B*H*W = 131072 tokens.
#define K_CODES 512
#define N_TOK   131072
#define ZQ_ELEMS 8388608   // 32*64*64*64

__device__ __forceinline__ uint32_t rotl32(uint32_t x, int d) {
  return (x << d) | (x >> (32 - d));
}

// JAX threefry2x32, key = (0, 42)  [jax.random.key(42) -> (hi,lo)=(0,42)]
// Partitionable 32-bit path: bits = out0 ^ out1 for counter (hi, lo) = (i>>32, i&0xffffffff).
__device__ __forceinline__ uint32_t tf_bits_xor(uint32_t hi, uint32_t lo) {
  const uint32_t ks0 = 0u;
  const uint32_t ks1 = 42u;
  const uint32_t ks2 = 0x1BD11BDAu ^ 0u ^ 42u;
  uint32_t x0 = hi + ks0;
  uint32_t x1 = lo + ks1;
#define TFR(r) { x0 += x1; x1 = rotl32(x1, (r)); x1 ^= x0; }
  TFR(13) TFR(15) TFR(26) TFR(6)
  x0 += ks1; x1 += ks2 + 1u;
  TFR(17) TFR(29) TFR(16) TFR(24)
  x0 += ks2; x1 += ks0 + 2u;
  TFR(13) TFR(15) TFR(26) TFR(6)
  x0 += ks0; x1 += ks1 + 3u;
  TFR(17) TFR(29) TFR(16) TFR(24)
  x0 += ks1; x1 += ks2 + 4u;
  TFR(13) TFR(15) TFR(26) TFR(6)
  x0 += ks2; x1 += ks0 + 5u;
#undef TFR
  return x0 ^ x1;
}

// gumbel = -log(-log(uniform)), uniform = max((bits>>9)*2^-23 (+tiny), tiny)
// Matches JAX: floats = bitcast((bits>>9)|0x3F800000) - 1.0 ; u = max(tiny, floats*1.0 + tiny)
__device__ __forceinline__ float gumbel_from_bits(uint32_t bits) {
  float u0 = (float)(bits >> 9) * 0x1p-23f;
  float u  = fmaxf(u0 + 1.17549435e-38f, 1.17549435e-38f);
  float nl = -logf(u);
  return -logf(nl);
}

// ---------------- kernel 0: row-normalize codebook ----------------
__global__ void k_norm(const float* __restrict__ w, float* __restrict__ embn) {
  int k = blockIdx.x;   // 512 rows
  int d = threadIdx.x;  // 64 lanes
  float v = w[(k << 6) + d];
  float s = v * v;
#pragma unroll
  for (int off = 1; off < 64; off <<= 1) s += __shfl_xor(s, off);
  float n = sqrtf(s);
  embn[(k << 6) + d] = v / n;
}

// ---------------- kernel 1: fused sims + gumbel argmax ----------------
__global__ __launch_bounds__(256) void k_argmax(
    const float* __restrict__ z_e, const float* __restrict__ embn,
    const float* __restrict__ kappa_p, int* __restrict__ idx_ws,
    float* __restrict__ partials, float* __restrict__ out_idx) {
  const float kappa = kappa_p[0];
  int t = blockIdx.x * 256 + threadIdx.x;         // token id
  int b = t >> 12, rem = t & 4095, h = rem >> 6, w = rem & 63;
  const float* zp = z_e + (b << 18) + (h << 6) + w;  // z_e[b, d, h, w], stride 4096 in d

  float z[64];
#pragma unroll
  for (int d = 0; d < 64; ++d) z[d] = zp[d << 12];

  float best = -INFINITY, bsim = 0.0f;
  int bk = 0;
  uint32_t base = (uint32_t)t * (uint32_t)K_CODES;

  for (int k = 0; k < K_CODES; ++k) {
    const float* e = embn + (k << 6);   // wave-uniform address -> scalar loads
    float s0 = 0.f, s1 = 0.f, s2 = 0.f, s3 = 0.f;
#pragma unroll
    for (int d = 0; d < 64; d += 4) {
      s0 = fmaf(z[d + 0], e[d + 0], s0);
      s1 = fmaf(z[d + 1], e[d + 1], s1);
      s2 = fmaf(z[d + 2], e[d + 2], s2);
      s3 = fmaf(z[d + 3], e[d + 3], s3);
    }
    float s = (s0 + s1) + (s2 + s3);
    float g = gumbel_from_bits(tf_bits_xor(0u, base + (uint32_t)k));
    float v = g + kappa * s;            // argmax(gumbel + logits), first occurrence on ties
    if (v > best) { best = v; bk = k; bsim = s; }
  }

  idx_ws[t] = bk;
  out_idx[t] = (float)bk;

  // deterministic block reduction of kappa*(1 - chosen_sim)
  float r = kappa * (1.0f - bsim);
#pragma unroll
  for (int off = 32; off; off >>= 1) r += __shfl_down(r, off);
  __shared__ float lds[4];
  int lane = threadIdx.x & 63, wid = threadIdx.x >> 6;
  if (lane == 0) lds[wid] = r;
  __syncthreads();
  if (threadIdx.x == 0) partials[blockIdx.x] = (lds[0] + lds[1]) + (lds[2] + lds[3]);
}

// ---------------- kernel 2: reduce partials -> reg ----------------
__global__ void k_reg(const float* __restrict__ partials,
                      float* __restrict__ out_reg) {
  int lane = threadIdx.x;  // 64
  float s = 0.f;
#pragma unroll
  for (int j = 0; j < 8; ++j) s += partials[lane + (j << 6)];
#pragma unroll
  for (int off = 1; off < 64; off <<= 1) s += __shfl_xor(s, off);
  if (lane == 0) out_reg[0] = s * (1.0f / 131072.0f);
}

// ---------------- kernel 3: gather z_q ----------------
__global__ __launch_bounds__(256) void k_gather(
    const float* __restrict__ embn, const int* __restrict__ idx_ws,
    float* __restrict__ out_zq) {
  int e = blockIdx.x * 256 + threadIdx.x;   // < 2^23
  int w = e & 63, h = (e >> 6) & 63, d = (e >> 12) & 63, b = e >> 18;
  int t = (b << 12) | (h << 6) | w;
  int idx = idx_ws[t];
  out_zq[e] = embn[(idx << 6) + d];
}

extern "C" void kernel_launch(void* const* d_in, const int* in_sizes, int n_in,
                              void* d_out, int out_size, void* d_ws, size_t ws_size,
                              hipStream_t stream) {
  const float* z_e    = (const float*)d_in[0];
  const float* emb_w  = (const float*)d_in[1];
  const float* kappa  = (const float*)d_in[2];

  // workspace layout
  float* embn     = (float*)d_ws;                              // 32768 f32 (128 KB)
  int*   idx_ws   = (int*)((char*)d_ws + 131072);              // 131072 i32 (512 KB)
  float* partials = (float*)((char*)d_ws + 131072 + 524288);   // 512 f32

  float* out     = (float*)d_out;          // float32 outputs, concatenated
  float* out_zq  = out;                    // [8388608]
  float* out_reg = out + ZQ_ELEMS;         // [1]
  float* out_idx = out + ZQ_ELEMS + 1;     // [131072]  (indices as floats)

  k_norm  <<<K_CODES, 64, 0, stream>>>(emb_w, embn);
  k_argmax<<<N_TOK / 256, 256, 0, stream>>>(z_e, embn, kappa, idx_ws, partials, out_idx);
  k_reg   <<<1, 64, 0, stream>>>(partials, out_reg);
  k_gather<<<ZQ_ELEMS / 256, 256, 0, stream>>>(embn, idx_ws, out_zq);
}